// Round 1
// baseline (591.949 us; speedup 1.0000x reference)
//
#include <hip/hip_runtime.h>
#include <hip/hip_bf16.h>

#define HEADS 16
#define B_    8
#define H_    2048
#define L_    1024
#define DK    128   // H_/HEADS

typedef __attribute__((ext_vector_type(8))) __bf16 bf16x8;
typedef __attribute__((ext_vector_type(4))) float  f32x4;

// ---------------------------------------------------------------------------
// Kernel 0a: qwb[bh][j] = sum_d q[b, head*DK+d] * Wq[d][j] + bias[j]
// Wq = attn_w rows [0,DK)
// ---------------------------------------------------------------------------
__global__ void prep_qwb_kernel(const float* __restrict__ query,
                                const float* __restrict__ attn_w,
                                const float* __restrict__ bias,
                                float* __restrict__ qwb) {
  __shared__ float qv[DK];
  const int bh   = blockIdx.x;          // 0..127
  const int b    = bh >> 4;
  const int head = bh & 15;
  const int tid  = threadIdx.x;
  if (tid < DK) qv[tid] = query[b * H_ + head * DK + tid];
  __syncthreads();
  for (int j = tid; j < H_; j += blockDim.x) {
    float acc = bias[j];
#pragma unroll 8
    for (int d = 0; d < DK; ++d) acc += qv[d] * attn_w[d * H_ + j];
    qwb[bh * H_ + j] = acc;
  }
}

// ---------------------------------------------------------------------------
// Kernel 0b: wkt[n][k] = (bf16) attn_w[DK + k][n]   (Wk transposed, bf16)
// ---------------------------------------------------------------------------
__global__ void prep_wkt_kernel(const float* __restrict__ attn_w,
                                __bf16* __restrict__ wkt) {
  const int idx = blockIdx.x * blockDim.x + threadIdx.x;   // 0 .. H_*DK-1
  const int k = idx / H_;       // consecutive threads -> consecutive n (coalesced read)
  const int n = idx % H_;
  wkt[n * DK + k] = (__bf16)attn_w[(DK + k) * H_ + n];
}

// ---------------------------------------------------------------------------
// Kernel 1: logits[bh][l] = sum_j relu( (K @ Wk)[l][j] + qwb[bh][j] ) * score[j]
// Block = (ltile, bh); 4 waves, each owns 16 rows of l. MFMA 16x16x32 bf16.
// A-fragments (16 rows x K=128) loaded once, reused for all 128 N-chunks.
// ---------------------------------------------------------------------------
__global__ void __launch_bounds__(256)
logits_kernel(const float* __restrict__ feed,
              const __bf16* __restrict__ wkt,
              const float* __restrict__ qwb,
              const float* __restrict__ score,
              float* __restrict__ logits) {
  const int ltile = blockIdx.x;     // 0..15
  const int bh    = blockIdx.y;     // 0..127
  const int b     = bh >> 4;
  const int head  = bh & 15;
  const int tid   = threadIdx.x;
  const int wave  = tid >> 6;
  const int lane  = tid & 63;
  const int row   = lane & 15;      // A row / B col / D col
  const int g     = lane >> 4;      // k-group 0..3

  // ---- A fragments: feed_hiddens[l, b, head*DK + k], k = ks*32 + g*8 + i ----
  const int l = ltile * 64 + wave * 16 + row;
  const float* fh = feed + (size_t)l * (B_ * H_) + b * H_ + head * DK;
  bf16x8 aF[4];
#pragma unroll
  for (int ks = 0; ks < 4; ++ks) {
    const int k0 = ks * 32 + g * 8;
    float4 x = *(const float4*)(fh + k0);
    float4 y = *(const float4*)(fh + k0 + 4);
    bf16x8 t;
    t[0] = (__bf16)x.x; t[1] = (__bf16)x.y; t[2] = (__bf16)x.z; t[3] = (__bf16)x.w;
    t[4] = (__bf16)y.x; t[5] = (__bf16)y.y; t[6] = (__bf16)y.z; t[7] = (__bf16)y.w;
    aF[ks] = t;
  }

  const float*  qrow = qwb + bh * H_;
  const __bf16* wb   = wkt + (size_t)row * DK + g * 8;  // col=row (lane&15), + chunk*16*DK

  float lacc0 = 0.f, lacc1 = 0.f, lacc2 = 0.f, lacc3 = 0.f;

#pragma unroll 2
  for (int nc = 0; nc < H_ / 16; ++nc) {
    const __bf16* wp = wb + (size_t)nc * 16 * DK;
    f32x4 d = {0.f, 0.f, 0.f, 0.f};
#pragma unroll
    for (int ks = 0; ks < 4; ++ks) {
      bf16x8 bF = *(const bf16x8*)(wp + ks * 32);
      d = __builtin_amdgcn_mfma_f32_16x16x32_bf16(aF[ks], bF, d, 0, 0, 0);
    }
    const int n  = nc * 16 + row;      // D col = lane&15
    const float qb = qrow[n];
    const float sc = score[n];
    lacc0 += fmaxf(d[0] + qb, 0.f) * sc;
    lacc1 += fmaxf(d[1] + qb, 0.f) * sc;
    lacc2 += fmaxf(d[2] + qb, 0.f) * sc;
    lacc3 += fmaxf(d[3] + qb, 0.f) * sc;
  }

  // Reduce over the 16 columns (lanes within each k-group share D rows g*4+r)
#pragma unroll
  for (int off = 1; off < 16; off <<= 1) {
    lacc0 += __shfl_xor(lacc0, off);
    lacc1 += __shfl_xor(lacc1, off);
    lacc2 += __shfl_xor(lacc2, off);
    lacc3 += __shfl_xor(lacc3, off);
  }
  if (row == 0) {
    const int base = bh * L_ + ltile * 64 + wave * 16 + g * 4;
    logits[base + 0] = lacc0;
    logits[base + 1] = lacc1;
    logits[base + 2] = lacc2;
    logits[base + 3] = lacc3;
  }
}

// ---------------------------------------------------------------------------
// Kernel 2: per (b,head): softmax over L, then out[d] = sum_l a[l]*v[l,b,hd+d]
// ---------------------------------------------------------------------------
__global__ void __launch_bounds__(512)
softmax_pv_kernel(const float* __restrict__ logits,
                  const float* __restrict__ values,
                  float* __restrict__ out) {
  const int bh   = blockIdx.x;
  const int b    = bh >> 4;
  const int head = bh & 15;
  const int tid  = threadIdx.x;

  __shared__ float sl[L_];
  __shared__ float sred[8];
  __shared__ float sscal;
  __shared__ float pacc[512];

  float m = -1e30f;
  for (int i = tid; i < L_; i += 512) {
    float v = logits[bh * L_ + i];
    sl[i] = v;
    m = fmaxf(m, v);
  }
#pragma unroll
  for (int off = 32; off > 0; off >>= 1) m = fmaxf(m, __shfl_xor(m, off));
  if ((tid & 63) == 0) sred[tid >> 6] = m;
  __syncthreads();
  if (tid == 0) {
    float mm = sred[0];
    for (int i = 1; i < 8; ++i) mm = fmaxf(mm, sred[i]);
    sscal = mm;
  }
  __syncthreads();
  const float mx = sscal;

  float s = 0.f;
  for (int i = tid; i < L_; i += 512) {
    float e = __expf(sl[i] - mx);
    sl[i] = e;
    s += e;
  }
#pragma unroll
  for (int off = 32; off > 0; off >>= 1) s += __shfl_xor(s, off);
  if ((tid & 63) == 0) sred[tid >> 6] = s;
  __syncthreads();
  if (tid == 0) {
    float t = 0.f;
    for (int i = 0; i < 8; ++i) t += sred[i];
    sscal = 1.0f / t;
  }
  __syncthreads();
  const float inv = sscal;

  // PV: 128 d-columns x 4 l-subsets
  const int d    = tid & 127;
  const int lsub = tid >> 7;      // 0..3
  const float* vp = values + (size_t)b * H_ + head * DK + d;
  float acc = 0.f;
  for (int ll = lsub; ll < L_; ll += 4)
    acc += sl[ll] * vp[(size_t)ll * (B_ * H_)];
  pacc[tid] = acc;
  __syncthreads();
  if (lsub == 0) {
    float t = (pacc[d] + pacc[128 + d]) + (pacc[256 + d] + pacc[384 + d]);
    out[b * H_ + head * DK + d] = t * inv;
  }
}

// ---------------------------------------------------------------------------
extern "C" void kernel_launch(void* const* d_in, const int* in_sizes, int n_in,
                              void* d_out, int out_size, void* d_ws, size_t ws_size,
                              hipStream_t stream) {
  const float* query  = (const float*)d_in[0];
  const float* feed   = (const float*)d_in[1];
  const float* values = (const float*)d_in[2];
  const float* attn_w = (const float*)d_in[3];
  const float* bias   = (const float*)d_in[4];
  const float* score  = (const float*)d_in[5];
  float* out = (float*)d_out;

  // Workspace layout: qwb (1 MB f32) | wkt (512 KB bf16) | logits (512 KB f32)
  float*  qwb    = (float*)d_ws;
  __bf16* wkt    = (__bf16*)((char*)d_ws + (size_t)(B_ * HEADS * H_) * sizeof(float));
  float*  logits = (float*)((char*)wkt + (size_t)(H_ * DK) * sizeof(__bf16));

  prep_qwb_kernel<<<B_ * HEADS, 256, 0, stream>>>(query, attn_w, bias, qwb);
  prep_wkt_kernel<<<(H_ * DK) / 256, 256, 0, stream>>>(attn_w, wkt);
  logits_kernel<<<dim3(L_ / 64, B_ * HEADS), 256, 0, stream>>>(feed, wkt, qwb, score, logits);
  softmax_pv_kernel<<<B_ * HEADS, 512, 0, stream>>>(logits, values, out);
}

// Round 2
// 126.012 us; speedup vs baseline: 4.6976x; 4.6976x over previous
//
#include <hip/hip_runtime.h>
#include <hip/hip_bf16.h>

#define HEADS 16
#define B_    8
#define H_    2048
#define L_    1024
#define DK    128   // H_/HEADS

typedef __attribute__((ext_vector_type(8))) __bf16 bf16x8;
typedef __attribute__((ext_vector_type(4))) float  f32x4;

// ---------------------------------------------------------------------------
// Kernel 0a: qwb[bh][j] = sum_d q[b, head*DK+d] * Wq[d][j] + bias[j]
// Grid (8 j-tiles, 16 bh-groups); each block: 8 bh x 256 j, Wq read coalesced.
// ---------------------------------------------------------------------------
__global__ void __launch_bounds__(256)
prep_qwb_kernel(const float* __restrict__ query,
                const float* __restrict__ attn_w,
                const float* __restrict__ bias,
                float* __restrict__ qwb) {
  const int jt  = blockIdx.x;   // 0..7
  const int bg  = blockIdx.y;   // 0..15
  const int tid = threadIdx.x;
  __shared__ float qv[8][DK];
  for (int i = tid; i < 8 * DK; i += 256) {
    const int bh = bg * 8 + (i >> 7);
    const int d  = i & 127;
    const int b = bh >> 4, head = bh & 15;
    qv[i >> 7][d] = query[b * H_ + head * DK + d];
  }
  __syncthreads();
  const int j = jt * 256 + tid;
  const float bj = bias[j];
  float acc[8];
#pragma unroll
  for (int u = 0; u < 8; ++u) acc[u] = bj;
  for (int d = 0; d < DK; ++d) {
    const float wv = attn_w[d * H_ + j];
#pragma unroll
    for (int u = 0; u < 8; ++u) acc[u] += qv[u][d] * wv;
  }
#pragma unroll
  for (int u = 0; u < 8; ++u) qwb[(size_t)(bg * 8 + u) * H_ + j] = acc[u];
}

// ---------------------------------------------------------------------------
// Kernel 0b: Wk -> bf16 in MFMA *fragment order*:
// wktf[((nc*4+ks)*64 + lane)*8 + i] = Wk[k][n],
//   n = nc*16 + (lane&15), k = ks*32 + (lane>>4)*8 + i
// so the logits kernel's B-fragment load is base + lane*16B (fully coalesced).
// ---------------------------------------------------------------------------
__global__ void prep_wktf_kernel(const float* __restrict__ attn_w,
                                 __bf16* __restrict__ wktf) {
  const int t = blockIdx.x * blockDim.x + threadIdx.x;   // 0..32767
  const int lane  = t & 63;
  const int chunk = t >> 6;          // nc*4 + ks
  const int ks = chunk & 3;
  const int nc = chunk >> 2;
  const int row = lane & 15, g = lane >> 4;
  const int n  = nc * 16 + row;
  const int k0 = ks * 32 + g * 8;
  bf16x8 v;
#pragma unroll
  for (int i = 0; i < 8; ++i)
    v[i] = (__bf16)attn_w[(size_t)(DK + k0 + i) * H_ + n];
  *(bf16x8*)(wktf + (size_t)t * 8) = v;
}

// ---------------------------------------------------------------------------
// Kernel 1: logits[bh][l] = sum_n relu( (K @ Wk)[l][n] + qwb[bh][n] ) * score[n]
// Block = 256 thr (4 waves), owns 128 rows of one bh; wave owns 32 rows
// (2 x 16-row subtiles sharing each B fragment). B loads coalesced from wktf.
// qwb folded into MFMA accumulator init.
// ---------------------------------------------------------------------------
__global__ void __launch_bounds__(256, 4)
logits_kernel(const float* __restrict__ feed,
              const __bf16* __restrict__ wktf,
              const float* __restrict__ qwb,
              const float* __restrict__ score,
              float* __restrict__ logits) {
  const int ltile = blockIdx.x;     // 0..7 (128 rows each)
  const int bh    = blockIdx.y;     // 0..127
  const int b     = bh >> 4;
  const int head  = bh & 15;
  const int tid   = threadIdx.x;
  const int wave  = tid >> 6;
  const int lane  = tid & 63;
  const int row   = lane & 15;      // A row / B col / D col
  const int g     = lane >> 4;      // k-group 0..3

  // A fragments: 2 subtiles x 4 k-steps
  bf16x8 aF[2][4];
#pragma unroll
  for (int s = 0; s < 2; ++s) {
    const int l = ltile * 128 + wave * 32 + s * 16 + row;
    const float* fh = feed + (size_t)l * (B_ * H_) + b * H_ + head * DK;
#pragma unroll
    for (int ks = 0; ks < 4; ++ks) {
      const int k0 = ks * 32 + g * 8;
      float4 x = *(const float4*)(fh + k0);
      float4 y = *(const float4*)(fh + k0 + 4);
      bf16x8 t;
      t[0] = (__bf16)x.x; t[1] = (__bf16)x.y; t[2] = (__bf16)x.z; t[3] = (__bf16)x.w;
      t[4] = (__bf16)y.x; t[5] = (__bf16)y.y; t[6] = (__bf16)y.z; t[7] = (__bf16)y.w;
      aF[s][ks] = t;
    }
  }

  const float* qrow = qwb + (size_t)bh * H_;
  float lacc[2][4] = {{0.f, 0.f, 0.f, 0.f}, {0.f, 0.f, 0.f, 0.f}};

#pragma unroll 2
  for (int nc = 0; nc < H_ / 16; ++nc) {
    const __bf16* wp = wktf + ((size_t)nc * 256 + lane) * 8;
    bf16x8 bF[4];
#pragma unroll
    for (int ks = 0; ks < 4; ++ks)
      bF[ks] = *(const bf16x8*)(wp + (size_t)ks * 512);
    const int n  = nc * 16 + row;
    const float qb = qrow[n];
    const float sc = score[n];
    f32x4 d0 = {qb, qb, qb, qb};
    f32x4 d1 = {qb, qb, qb, qb};
#pragma unroll
    for (int ks = 0; ks < 4; ++ks) {
      d0 = __builtin_amdgcn_mfma_f32_16x16x32_bf16(aF[0][ks], bF[ks], d0, 0, 0, 0);
      d1 = __builtin_amdgcn_mfma_f32_16x16x32_bf16(aF[1][ks], bF[ks], d1, 0, 0, 0);
    }
#pragma unroll
    for (int i = 0; i < 4; ++i) {
      lacc[0][i] += fmaxf(d0[i], 0.f) * sc;
      lacc[1][i] += fmaxf(d1[i], 0.f) * sc;
    }
  }

  // Reduce over the 16 D-columns (lanes 0..15 within each k-group)
#pragma unroll
  for (int s = 0; s < 2; ++s) {
#pragma unroll
    for (int i = 0; i < 4; ++i) {
      float v = lacc[s][i];
#pragma unroll
      for (int off = 1; off < 16; off <<= 1) v += __shfl_xor(v, off);
      lacc[s][i] = v;
    }
  }
  if (row == 0) {
#pragma unroll
    for (int s = 0; s < 2; ++s) {
      const int base = bh * L_ + ltile * 128 + wave * 32 + s * 16 + g * 4;
#pragma unroll
      for (int i = 0; i < 4; ++i) logits[base + i] = lacc[s][i];
    }
  }
}

// ---------------------------------------------------------------------------
// Kernel 2: per (b,head): softmax over L, then out[d] = sum_l a[l]*v[l,b,hd+d]
// ---------------------------------------------------------------------------
__global__ void __launch_bounds__(512)
softmax_pv_kernel(const float* __restrict__ logits,
                  const float* __restrict__ values,
                  float* __restrict__ out) {
  const int bh   = blockIdx.x;
  const int b    = bh >> 4;
  const int head = bh & 15;
  const int tid  = threadIdx.x;

  __shared__ float sl[L_];
  __shared__ float sred[8];
  __shared__ float sscal;
  __shared__ float pacc[16][DK];

  float m = -1e30f;
  for (int i = tid; i < L_; i += 512) {
    float v = logits[(size_t)bh * L_ + i];
    sl[i] = v;
    m = fmaxf(m, v);
  }
#pragma unroll
  for (int off = 32; off > 0; off >>= 1) m = fmaxf(m, __shfl_xor(m, off));
  if ((tid & 63) == 0) sred[tid >> 6] = m;
  __syncthreads();
  if (tid == 0) {
    float mm = sred[0];
    for (int i = 1; i < 8; ++i) mm = fmaxf(mm, sred[i]);
    sscal = mm;
  }
  __syncthreads();
  const float mx = sscal;

  float s = 0.f;
  for (int i = tid; i < L_; i += 512) {
    float e = __expf(sl[i] - mx);
    sl[i] = e;
    s += e;
  }
#pragma unroll
  for (int off = 32; off > 0; off >>= 1) s += __shfl_xor(s, off);
  if ((tid & 63) == 0) sred[tid >> 6] = s;
  __syncthreads();
  if (tid == 0) {
    float t = 0.f;
    for (int i = 0; i < 8; ++i) t += sred[i];
    sscal = 1.0f / t;
  }
  __syncthreads();
  const float inv = sscal;

  // PV: float4 over d, 16 l-subsets
  const int dq   = (tid & 31) * 4;    // float4 col within DK
  const int lsub = tid >> 5;          // 0..15
  const float4* vp = (const float4*)(values + (size_t)b * H_ + head * DK + dq);
  float4 acc = {0.f, 0.f, 0.f, 0.f};
  for (int ll = lsub; ll < L_; ll += 16) {
    const float w = sl[ll];
    float4 v = vp[(size_t)ll * (B_ * H_ / 4)];
    acc.x += w * v.x; acc.y += w * v.y; acc.z += w * v.z; acc.w += w * v.w;
  }
  *(float4*)&pacc[lsub][dq] = acc;
  __syncthreads();
  if (tid < DK) {
    float t = 0.f;
#pragma unroll
    for (int s2 = 0; s2 < 16; ++s2) t += pacc[s2][tid];
    out[b * H_ + head * DK + tid] = t * inv;
  }
}

// ---------------------------------------------------------------------------
extern "C" void kernel_launch(void* const* d_in, const int* in_sizes, int n_in,
                              void* d_out, int out_size, void* d_ws, size_t ws_size,
                              hipStream_t stream) {
  const float* query  = (const float*)d_in[0];
  const float* feed   = (const float*)d_in[1];
  const float* values = (const float*)d_in[2];
  const float* attn_w = (const float*)d_in[3];
  const float* bias   = (const float*)d_in[4];
  const float* score  = (const float*)d_in[5];
  float* out = (float*)d_out;

  // Workspace: qwb (1 MB f32) | wktf (512 KB bf16) | logits (512 KB f32)
  float*  qwb    = (float*)d_ws;
  __bf16* wktf   = (__bf16*)((char*)d_ws + (size_t)(B_ * HEADS * H_) * sizeof(float));
  float*  logits = (float*)((char*)wktf + (size_t)(H_ * DK) * sizeof(__bf16));

  prep_qwb_kernel<<<dim3(H_ / 256, B_ * HEADS / 8), 256, 0, stream>>>(query, attn_w, bias, qwb);
  prep_wktf_kernel<<<(H_ * DK / 8) / 256, 256, 0, stream>>>(attn_w, wktf);
  logits_kernel<<<dim3(L_ / 128, B_ * HEADS), 256, 0, stream>>>(feed, wktf, qwb, score, logits);
  softmax_pv_kernel<<<B_ * HEADS, 512, 0, stream>>>(logits, values, out);
}